// Round 1
// 816.794 us; speedup vs baseline: 2.2297x; 2.2297x over previous
//
#include <hip/hip_runtime.h>
#include <stdint.h>

// LSTM: B=65536, T=28, IN=28, H=128. Final hidden [B,H] output.
// Restructured: block = 32 batch rows x 28 timesteps, 4 waves/block.
// Wave w owns output columns [32w, 32w+32) for ALL FOUR gates -> gate values
// stay in fp32 registers (no LDS gate exchange, one barrier/step).
// Weights pre-packed to bf16 (K padded to 160) in d_ws by a one-shot kernel;
// B-fragments streamed from L2 each step (saves ~160 persistent VGPRs ->
// 2 waves/SIMD instead of 1).
// Dtype self-detection unchanged: detect_dtype -> flag in d_ws[0].

#define T_STEPS   28
#define HDIM      128
#define KIN       156            // H + IN
#define KPAD      160            // K padded for packed weights
#define MB        32             // batch rows per block
#define KSTEPS    5              // K=160: 4x32 (h) + 1x32 (x: 28 real + 4 pad)
#define HLDS_ST   136            // h_lds row stride in shorts (128 + 8 pad)
#define XLDS_ST   40             // x_lds row stride in shorts (32 + 8 pad)

#define WS_WOFF   1024                       // byte offset of packed weights in d_ws
#define WS_BOFF   (1024 + 4*HDIM*KPAD*2)     // byte offset of fp32 biases

typedef __attribute__((ext_vector_type(8))) short  short8;
typedef __attribute__((ext_vector_type(4))) float  floatx4;

union Frag { short8 f; uint2 u2[2]; unsigned short s[8]; };
union Pk4  { uint2 u2; unsigned short s[4]; };

__device__ __forceinline__ float bf2f(unsigned short v) {
    union { uint32_t u; float f; } c; c.u = ((uint32_t)v) << 16; return c.f;
}
__device__ __forceinline__ unsigned short f2bf(float x) {
    union { float f; uint32_t u; } c; c.f = x;          // RNE bf16 (finite inputs)
    return (unsigned short)((c.u + 0x7FFFu + ((c.u >> 16) & 1u)) >> 16);
}
__device__ __forceinline__ float fast_rcp(float x) { return __builtin_amdgcn_rcpf(x); }
// NaN-free at extremes: exp->inf => rcp->0; exp->0 => rcp(1)=1.
__device__ __forceinline__ float sigm(float x)   { return fast_rcp(1.0f + __expf(-x)); }
__device__ __forceinline__ float tanh_f(float x) {
    float e = __expf(2.0f * x);
    return 1.0f - 2.0f * fast_rcp(e + 1.0f);
}

// bf16 |W_f| <= 0.08 -> exponent field <= 123 always. fp32 read as shorts:
// mantissa halves ~uniform -> exponent field >= 127 with p~0.5/short.
__global__ void detect_dtype(const unsigned short* __restrict__ wf, int* __restrict__ flag) {
    const int lane = threadIdx.x;
    bool big = false;
    #pragma unroll
    for (int i = 0; i < 4; ++i) {
        unsigned e = (wf[lane * 4 + i] >> 7) & 0xFFu;
        if (e >= 127u) big = true;
    }
    const int isfp32 = __any(big) ? 1 : 0;
    if (lane == 0) *flag = isfp32;
}

// One-shot: pack W[4][128][156] (fp32 or bf16) -> bf16 [4][128][160] (zero pad),
// and biases -> fp32 [4][128]. Grid: 320 blocks x 256 = 81920 threads.
template <bool FP32>
__global__ void pack_weights(const void* __restrict__ Wf_, const void* __restrict__ bf_,
                             const void* __restrict__ Wi_, const void* __restrict__ bi_,
                             const void* __restrict__ Wc_, const void* __restrict__ bc_,
                             const void* __restrict__ Wo_, const void* __restrict__ bo_,
                             void* __restrict__ ws, const int* __restrict__ flag)
{
    if (*flag != (FP32 ? 1 : 0)) return;
    unsigned short* wpk = (unsigned short*)((char*)ws + WS_WOFF);
    float*          bpk = (float*)((char*)ws + WS_BOFF);

    const int gid = blockIdx.x * 256 + threadIdx.x;        // 0..81919
    const int g   = gid / (HDIM * KPAD);                   // uniform per block (80 blocks/gate)
    const int rem = gid % (HDIM * KPAD);
    const int n   = rem / KPAD;
    const int k   = rem % KPAD;
    const void* Wg = (g == 0) ? Wf_ : (g == 1) ? Wi_ : (g == 2) ? Wc_ : Wo_;

    unsigned short v = 0;
    if (k < KIN) {
        if constexpr (FP32) v = f2bf(((const float*)Wg)[n * KIN + k]);
        else                v = ((const unsigned short*)Wg)[n * KIN + k];
    }
    wpk[gid] = v;

    if (gid < 4 * HDIM) {
        const int gg = gid >> 7, nn = gid & 127;
        const void* bg = (gg == 0) ? bf_ : (gg == 1) ? bi_ : (gg == 2) ? bc_ : bo_;
        if constexpr (FP32) bpk[gid] = ((const float*)bg)[nn];
        else                bpk[gid] = bf2f(((const unsigned short*)bg)[nn]);
    }
}

template <bool FP32>
__global__ __launch_bounds__(256, 2)
void lstm_fused(const void* __restrict__ x_, const void* __restrict__ ws,
                void* __restrict__ out_, const int* __restrict__ flag)
{
    if (*flag != (FP32 ? 1 : 0)) return;   // wrong-dtype variant: uniform exit

    __shared__ __align__(16) unsigned short h_lds[2][MB * HLDS_ST];   // 17408 B
    __shared__ __align__(16) unsigned short x_lds[2][MB * XLDS_ST];   //  5120 B

    const int tid  = threadIdx.x;
    const int wv   = tid >> 6;
    const int lane = tid & 63;
    const int q    = lane >> 4;    // quad
    const int cc   = lane & 15;
    const int b0   = blockIdx.x * MB;

    const unsigned short* wpk = (const unsigned short*)((const char*)ws + WS_WOFF);
    const float*          bpk = (const float*)((const char*)ws + WS_BOFF);
    // per-lane base into packed weights: row n = wv*32 + (n2*16) + cc, k-lane = q*8
    const unsigned short* wb  = wpk + (size_t)(wv * 32 + cc) * KPAD + q * 8;

    float bias_r[4][2];
    #pragma unroll
    for (int g = 0; g < 4; ++g)
        #pragma unroll
        for (int n2 = 0; n2 < 2; ++n2)
            bias_r[g][n2] = bpk[g * HDIM + wv * 32 + n2 * 16 + cc];

    // zero h buf0 (h0=0) and x pads (shorts 28..39 of each row stay 0 forever)
    for (int i = tid; i < MB * HLDS_ST; i += 256) h_lds[0][i] = 0;
    for (int i = tid; i < MB * XLDS_ST; i += 256) { x_lds[0][i] = 0; x_lds[1][i] = 0; }

    // x staging: 7 threads/row, 4 elems each -> 28 elems/row
    auto stage_x = [&](int ts, int buf) {
        if (tid < 224) {
            const int row = tid / 7, sub = tid % 7;
            const size_t off = (size_t)(b0 + row) * (T_STEPS * 28) + ts * 28 + sub * 4;
            Pk4 pk;
            if constexpr (FP32) {
                float4 v = *(const float4*)((const float*)x_ + off);
                pk.s[0] = f2bf(v.x); pk.s[1] = f2bf(v.y);
                pk.s[2] = f2bf(v.z); pk.s[3] = f2bf(v.w);
            } else {
                pk.u2 = *(const uint2*)((const unsigned short*)x_ + off);
            }
            *(uint2*)&x_lds[buf][row * XLDS_ST + sub * 4] = pk.u2;
        }
    };
    stage_x(0, 0);

    float c_st[2][2][4];                       // [mt][n2][r] cell state, fp32
    #pragma unroll
    for (int mt = 0; mt < 2; ++mt)
        #pragma unroll
        for (int n2 = 0; n2 < 2; ++n2)
            #pragma unroll
            for (int r = 0; r < 4; ++r) c_st[mt][n2][r] = 0.0f;

    __syncthreads();

    int cur = 0;
    #pragma unroll 1
    for (int t = 0; t < T_STEPS; ++t) {
        // prefetch next x tile into the other buffer (no reader until next step)
        if (t + 1 < T_STEPS) stage_x(t + 1, cur ^ 1);

        #pragma unroll
        for (int mt = 0; mt < 2; ++mt) {
            // ---- issue W group ks=0 early (L2-hit ~200cy hides under A-loads/init)
            Frag w0[8], w1[8];
            #pragma unroll
            for (int g = 0; g < 4; ++g)
                #pragma unroll
                for (int n2 = 0; n2 < 2; ++n2)
                    w0[g * 2 + n2].f = *(const short8*)(wb + (g * HDIM + n2 * 16) * KPAD);

            // ---- A fragments: h (4 groups) + x (1 group)
            Frag a[KSTEPS];
            #pragma unroll
            for (int ks = 0; ks < 4; ++ks)
                a[ks].f = *(const short8*)&h_lds[cur][(mt * 16 + cc) * HLDS_ST + ks * 32 + q * 8];
            a[4].f = *(const short8*)&x_lds[cur][(mt * 16 + cc) * XLDS_ST + q * 8];

            floatx4 acc[4][2];
            #pragma unroll
            for (int g = 0; g < 4; ++g)
                #pragma unroll
                for (int n2 = 0; n2 < 2; ++n2) {
                    const float bv = bias_r[g][n2];
                    acc[g][n2] = (floatx4){bv, bv, bv, bv};
                }

            // ---- MFMA: stream weight groups, double-buffered
            #pragma unroll
            for (int ks = 0; ks < KSTEPS; ++ks) {
                Frag* wc = (ks & 1) ? w1 : w0;
                Frag* wn = (ks & 1) ? w0 : w1;
                if (ks + 1 < KSTEPS) {
                    #pragma unroll
                    for (int g = 0; g < 4; ++g)
                        #pragma unroll
                        for (int n2 = 0; n2 < 2; ++n2)
                            wn[g * 2 + n2].f =
                                *(const short8*)(wb + (g * HDIM + n2 * 16) * KPAD + (ks + 1) * 32);
                }
                #pragma unroll
                for (int g = 0; g < 4; ++g)
                    #pragma unroll
                    for (int n2 = 0; n2 < 2; ++n2)
                        acc[g][n2] = __builtin_amdgcn_mfma_f32_16x16x32_bf16(
                            a[ks].f, wc[g * 2 + n2].f, acc[g][n2], 0, 0, 0);
            }

            // ---- gates in-register: activations + c,h update, write h to next buf
            #pragma unroll
            for (int n2 = 0; n2 < 2; ++n2) {
                const int j = wv * 32 + n2 * 16 + cc;
                #pragma unroll
                for (int r = 0; r < 4; ++r) {
                    const float fv = sigm(acc[0][n2][r]);
                    const float iv = sigm(acc[1][n2][r]);
                    const float nv = tanh_f(acc[2][n2][r]);
                    const float ov = sigm(acc[3][n2][r]);
                    const float cn = c_st[mt][n2][r] * fv + iv * nv;
                    c_st[mt][n2][r] = cn;
                    const float hv = ov * tanh_f(cn);
                    const int mrow = mt * 16 + q * 4 + r;
                    h_lds[cur ^ 1][mrow * HLDS_ST + j] = f2bf(hv);
                    if (t == T_STEPS - 1) {
                        const size_t oi = (size_t)(b0 + mrow) * HDIM + j;
                        if constexpr (FP32) ((float*)out_)[oi] = hv;
                        else                ((unsigned short*)out_)[oi] = f2bf(hv);
                    }
                }
            }
        }
        __syncthreads();     // single barrier: publishes h[cur^1] and x[cur^1]
        cur ^= 1;
    }
}

extern "C" void kernel_launch(void* const* d_in, const int* in_sizes, int n_in,
                              void* d_out, int out_size, void* d_ws, size_t ws_size,
                              hipStream_t stream) {
    int* flag = (int*)d_ws;
    detect_dtype<<<dim3(1), dim3(64), 0, stream>>>((const unsigned short*)d_in[1], flag);

    pack_weights<false><<<dim3(320), dim3(256), 0, stream>>>(
        d_in[1], d_in[2], d_in[3], d_in[4], d_in[5], d_in[6], d_in[7], d_in[8], d_ws, flag);
    pack_weights<true><<<dim3(320), dim3(256), 0, stream>>>(
        d_in[1], d_in[2], d_in[3], d_in[4], d_in[5], d_in[6], d_in[7], d_in[8], d_ws, flag);

    lstm_fused<false><<<dim3(65536 / MB), dim3(256), 0, stream>>>(d_in[0], d_ws, d_out, flag);
    lstm_fused<true><<<dim3(65536 / MB), dim3(256), 0, stream>>>(d_in[0], d_ws, d_out, flag);
}